// Round 1
// baseline (531.873 us; speedup 1.0000x reference)
//
#include <hip/hip_runtime.h>
#include <math.h>

// LIF spiking-neuron scan: N=65536 rows, T=512 sequential steps/row.
// d_out = [spikes (N*T) | mems (N*T)] fp32.
// One thread per row; float4 chunked with next-chunk prefetch.
// NUMERICS: must match numpy fp32 exactly on the hard-threshold decision,
// so FMA contraction is disabled on the recurrence and beta is computed
// via double-rounded sigmoid.

constexpr int N_BATCH = 65536;
constexpr int T_STEPS = 512;

__global__ __launch_bounds__(256) void lif_scan_kernel(
    const float* __restrict__ x,
    const float* __restrict__ beta_p,
    const float* __restrict__ thr_p,
    const float* __restrict__ init_u,
    float* __restrict__ out)
{
#pragma clang fp contract(off)
    const int n = blockIdx.x * blockDim.x + threadIdx.x;

    const float thr = thr_p[0];
    // sigmoid in double, round once to fp32 -> correctly-rounded 0.9f-ish
    const float beta = (float)(1.0 / (1.0 + exp(-(double)beta_p[0])));

    float mem = __fmul_rn(init_u[n], thr);  // mem0 = init_u * thr

    const float4* __restrict__ xr =
        (const float4*)(x + (size_t)n * T_STEPS);
    float4* __restrict__ sr =
        (float4*)(out + (size_t)n * T_STEPS);
    float4* __restrict__ mr =
        (float4*)(out + (size_t)N_BATCH * T_STEPS + (size_t)n * T_STEPS);

    constexpr int C = 4;                   // float4s per chunk = 16 steps
    constexpr int NCH = T_STEPS / (4 * C); // 32 chunks

    float4 cur[C];
#pragma unroll
    for (int j = 0; j < C; ++j) cur[j] = xr[j];

    for (int c = 0; c < NCH; ++c) {
        float4 nxt[C];
        if (c + 1 < NCH) {
#pragma unroll
            for (int j = 0; j < C; ++j) nxt[j] = xr[(c + 1) * C + j];
        }

        float4 sv[C], mv[C];
#pragma unroll
        for (int j = 0; j < C; ++j) {
            float xs[4] = {cur[j].x, cur[j].y, cur[j].z, cur[j].w};
            float ss[4], ms[4];
#pragma unroll
            for (int k = 0; k < 4; ++k) {
                const float mem_in  = mem;
                // beta*mem + x WITHOUT fma (match numpy rounding)
                const float mem_upd = __fadd_rn(__fmul_rn(beta, mem), xs[k]);
                const float surplus = __fsub_rn(mem_upd, thr);
                const float hard    = (surplus >= 0.0f) ? 1.0f : 0.0f;
                ss[k] = hard;      // spike forward value == hard
                ms[k] = mem_in;    // mems logs memory BEFORE the step
                mem = __fsub_rn(mem_upd, __fmul_rn(hard, thr));
            }
            sv[j] = make_float4(ss[0], ss[1], ss[2], ss[3]);
            mv[j] = make_float4(ms[0], ms[1], ms[2], ms[3]);
        }

#pragma unroll
        for (int j = 0; j < C; ++j) {
            sr[c * C + j] = sv[j];
            mr[c * C + j] = mv[j];
        }
#pragma unroll
        for (int j = 0; j < C; ++j) cur[j] = nxt[j];
    }
}

extern "C" void kernel_launch(void* const* d_in, const int* in_sizes, int n_in,
                              void* d_out, int out_size, void* d_ws, size_t ws_size,
                              hipStream_t stream) {
    const float* x      = (const float*)d_in[0];
    const float* beta_  = (const float*)d_in[1];
    const float* thresh = (const float*)d_in[2];
    const float* init_u = (const float*)d_in[3];
    float* out = (float*)d_out;

    dim3 block(256);
    dim3 grid(N_BATCH / 256);
    lif_scan_kernel<<<grid, block, 0, stream>>>(x, beta_, thresh, init_u, out);
}

// Round 2
// 453.615 us; speedup vs baseline: 1.1725x; 1.1725x over previous
//
#include <hip/hip_runtime.h>
#include <math.h>

// LIF spiking-neuron scan: N=65536 rows, T=512 sequential steps/row.
// d_out = [spikes (N*T) | mems (N*T)] fp32.
//
// R1 lesson: 64B-per-thread-per-visit chunks caused 2.2x HBM write
// amplification (128B L2 lines evicted half-dirty). This version uses
// 32-step chunks = 128B aligned contiguous per thread per output, with
// the 8 covering float4 stores issued back-to-back so lines leave L2
// fully dirty exactly once.
//
// NUMERICS: bit-exact vs numpy verified in R1 — no FMA contraction on the
// recurrence, sigmoid(beta_) double-rounded once to fp32. Do not change.

constexpr int N_BATCH = 65536;
constexpr int T_STEPS = 512;

__global__ __launch_bounds__(256) void lif_scan_kernel(
    const float* __restrict__ x,
    const float* __restrict__ beta_p,
    const float* __restrict__ thr_p,
    const float* __restrict__ init_u,
    float* __restrict__ out)
{
#pragma clang fp contract(off)
    const int n = blockIdx.x * blockDim.x + threadIdx.x;

    const float thr = thr_p[0];
    const float beta = (float)(1.0 / (1.0 + exp(-(double)beta_p[0])));

    float mem = __fmul_rn(init_u[n], thr);  // mem0 = init_u * thr

    const float4* __restrict__ xr =
        (const float4*)(x + (size_t)n * T_STEPS);
    float4* __restrict__ sr =
        (float4*)(out + (size_t)n * T_STEPS);
    float4* __restrict__ mr =
        (float4*)(out + (size_t)N_BATCH * T_STEPS + (size_t)n * T_STEPS);

    constexpr int C = 8;                   // float4s per chunk = 32 steps = 128B
    constexpr int NCH = T_STEPS / (4 * C); // 16 chunks

    float4 cur[C];
#pragma unroll
    for (int j = 0; j < C; ++j) cur[j] = xr[j];

    for (int c = 0; c < NCH; ++c) {
        float4 nxt[C];
        if (c + 1 < NCH) {   // wave-uniform branch (loop counter)
#pragma unroll
            for (int j = 0; j < C; ++j) nxt[j] = xr[(c + 1) * C + j];
        }

        float4 sv[C], mv[C];
#pragma unroll
        for (int j = 0; j < C; ++j) {
            float xs[4] = {cur[j].x, cur[j].y, cur[j].z, cur[j].w};
            float ss[4], ms[4];
#pragma unroll
            for (int k = 0; k < 4; ++k) {
                const float mem_in  = mem;
                // beta*mem + x WITHOUT fma (match numpy rounding)
                const float mem_upd = __fadd_rn(__fmul_rn(beta, mem), xs[k]);
                const float surplus = __fsub_rn(mem_upd, thr);
                const float hard    = (surplus >= 0.0f) ? 1.0f : 0.0f;
                ss[k] = hard;      // spike forward value == hard
                ms[k] = mem_in;    // mems logs memory BEFORE the step
                mem = __fsub_rn(mem_upd, __fmul_rn(hard, thr));
            }
            sv[j] = make_float4(ss[0], ss[1], ss[2], ss[3]);
            mv[j] = make_float4(ms[0], ms[1], ms[2], ms[3]);
        }

        // Back-to-back full-line stores: 8 x float4 = 128B contiguous per
        // thread per output -> each 128B L2 line goes fully dirty before
        // any chance of eviction.
#pragma unroll
        for (int j = 0; j < C; ++j) sr[c * C + j] = sv[j];
#pragma unroll
        for (int j = 0; j < C; ++j) mr[c * C + j] = mv[j];

#pragma unroll
        for (int j = 0; j < C; ++j) cur[j] = nxt[j];
    }
}

extern "C" void kernel_launch(void* const* d_in, const int* in_sizes, int n_in,
                              void* d_out, int out_size, void* d_ws, size_t ws_size,
                              hipStream_t stream) {
    const float* x      = (const float*)d_in[0];
    const float* beta_  = (const float*)d_in[1];
    const float* thresh = (const float*)d_in[2];
    const float* init_u = (const float*)d_in[3];
    float* out = (float*)d_out;

    dim3 block(256);
    dim3 grid(N_BATCH / 256);
    lif_scan_kernel<<<grid, block, 0, stream>>>(x, beta_, thresh, init_u, out);
}

// Round 3
// 370.400 us; speedup vs baseline: 1.4359x; 1.2247x over previous
//
#include <hip/hip_runtime.h>
#include <math.h>

// LIF spiking-neuron scan: N=65536 rows, T=512 sequential steps/row.
// d_out = [spikes (N*T) | mems (N*T)] fp32.
//
// R2 lesson: thread-per-row direct global I/O puts each wave's 64 lanes on
// 64 DIFFERENT 128B lines per instruction (2048B lane stride) -> per-line
// transaction cost caps us at ~2.5 TB/s. The harness's own fill kernel does
// full-line-per-instruction stores and hits 6 TB/s at 10% occupancy.
//
// R3 design: decouple compute layout (thread = row, serial over t) from
// memory layout via LDS staging. Global I/O is cooperative: lane group of 8
// covers one row's 128B chunk -> every dwordx4 instruction covers 8 FULL
// lines. Single-wave workgroups (64 threads): lockstep lanes + in-order DS
// ops make the LDS staging correct with NO __syncthreads(), so the
// next-chunk global prefetch stays in flight across compute (no
// vmcnt(0)-before-barrier drain). 1024 blocks = 4 independent
// pipelines/CU for latency overlap.
//
// NUMERICS: bit-exact vs numpy verified in R1/R2 — no FMA contraction on
// the recurrence, sigmoid(beta_) double-rounded once to fp32. Do not change.

constexpr int N_BATCH = 65536;
constexpr int T_STEPS = 512;
constexpr int BLOCK   = 64;              // ONE wave — wave-synchronous, no barriers
constexpr int ROWS    = 64;              // rows per block
constexpr int TILE    = 32;              // steps per chunk = 128B per row
constexpr int NCH     = T_STEPS / TILE;  // 16 chunks
constexpr int PAD     = TILE + 1;        // LDS row stride (floats): bank-conflict-free

__global__ __launch_bounds__(BLOCK) void lif_scan_kernel(
    const float* __restrict__ x,
    const float* __restrict__ beta_p,
    const float* __restrict__ thr_p,
    const float* __restrict__ init_u,
    float* __restrict__ out)
{
#pragma clang fp contract(off)
    __shared__ float xs [ROWS * PAD];   // x tile
    __shared__ float ssb[ROWS * PAD];   // spikes tile
    __shared__ float msb[ROWS * PAD];   // mems tile

    const int t    = threadIdx.x;       // 0..63
    const int base = blockIdx.x * ROWS;
    const int rsub = t >> 3;            // 0..7: row-within-pass for I/O role
    const int a    = t & 7;             // 0..7: float4 index within 128B chunk

    const float thr  = thr_p[0];
    const float beta = (float)(1.0 / (1.0 + exp(-(double)beta_p[0])));
    float mem = __fmul_rn(init_u[base + t], thr);   // mem0, row base+t

    const float4* __restrict__ xg = (const float4*)x;
    float4* __restrict__ sg = (float4*)out;
    float4* __restrict__ mg = (float4*)(out + (size_t)N_BATCH * T_STEPS);
    // row r's float4-row-pitch is 128; chunk c starts at float4 index c*8.

    float4 v[8];
    // prefetch chunk 0: pass p covers rows p*8..p*8+7; lanes 0-7 = one full
    // 128B line of row p*8 (and so on) -> 8 full lines per instruction.
#pragma unroll
    for (int p = 0; p < 8; ++p)
        v[p] = xg[(size_t)(base + p * 8 + rsub) * 128 + a];

    for (int c = 0; c < NCH; ++c) {
        // ---- stage x tile: regs -> LDS (row-major, +1 pad) ----
#pragma unroll
        for (int p = 0; p < 8; ++p) {
            const int r = p * 8 + rsub;
            float* dst = &xs[r * PAD + a * 4];
            dst[0] = v[p].x; dst[1] = v[p].y; dst[2] = v[p].z; dst[3] = v[p].w;
        }
        // ---- prefetch chunk c+1 (in flight across compute + store) ----
        if (c + 1 < NCH) {
#pragma unroll
            for (int p = 0; p < 8; ++p)
                v[p] = xg[(size_t)(base + p * 8 + rsub) * 128 + (c + 1) * 8 + a];
        }
        // ---- compute: thread t scans row base+t over 32 steps ----
        // (wave-synchronous: DS in-order + lockstep lanes; no barrier needed)
#pragma unroll
        for (int k = 0; k < TILE; ++k) {
            const float xv      = xs[t * PAD + k];
            const float mem_in  = mem;
            const float mem_upd = __fadd_rn(__fmul_rn(beta, mem), xv);
            const float surplus = __fsub_rn(mem_upd, thr);
            const float hard    = (surplus >= 0.0f) ? 1.0f : 0.0f;
            ssb[t * PAD + k] = hard;     // spike forward value == hard
            msb[t * PAD + k] = mem_in;   // mems logs memory BEFORE the step
            mem = __fsub_rn(mem_upd, __fmul_rn(hard, thr));
        }
        // ---- store stage: LDS -> global, 8 full lines per instruction ----
#pragma unroll
        for (int p = 0; p < 8; ++p) {
            const int r = p * 8 + rsub;
            const float* srow = &ssb[r * PAD + a * 4];
            const float* mrow = &msb[r * PAD + a * 4];
            const float4 sv = make_float4(srow[0], srow[1], srow[2], srow[3]);
            const float4 mv = make_float4(mrow[0], mrow[1], mrow[2], mrow[3]);
            const size_t gi = (size_t)(base + r) * 128 + (size_t)c * 8 + a;
            sg[gi] = sv;
            mg[gi] = mv;
        }
    }
}

extern "C" void kernel_launch(void* const* d_in, const int* in_sizes, int n_in,
                              void* d_out, int out_size, void* d_ws, size_t ws_size,
                              hipStream_t stream) {
    const float* x      = (const float*)d_in[0];
    const float* beta_  = (const float*)d_in[1];
    const float* thresh = (const float*)d_in[2];
    const float* init_u = (const float*)d_in[3];
    float* out = (float*)d_out;

    dim3 block(BLOCK);
    dim3 grid(N_BATCH / ROWS);   // 1024 blocks -> 4 per CU
    lif_scan_kernel<<<grid, block, 0, stream>>>(x, beta_, thresh, init_u, out);
}